// Round 1
// 1736.685 us; speedup vs baseline: 1.4422x; 1.4422x over previous
//
#include <hip/hip_runtime.h>

#define Tt 8192     // tokens B*S
#define Dd 2048     // model dim
#define Ee 8        // routed experts
#define Hh 1368     // hidden
#define Hp 1408     // hidden padded to 11*128

using short8  = __attribute__((ext_vector_type(8))) short;
using float4v = __attribute__((ext_vector_type(4))) float;

__device__ __forceinline__ unsigned short f2b(float f) {
  union { float f; unsigned u; } v; v.f = f;
  unsigned r = v.u + 0x7fffu + ((v.u >> 16) & 1u);
  return (unsigned short)(r >> 16);
}

// load 8 consecutive fp32, RNE to bf16, pack as short8
__device__ __forceinline__ short8 load_cvt8(const float* g) {
  const float4* p = (const float4*)g;
  float4 a = p[0], b = p[1];
  short8 r;
  unsigned short* q = (unsigned short*)&r;
  q[0] = f2b(a.x); q[1] = f2b(a.y); q[2] = f2b(a.z); q[3] = f2b(a.w);
  q[4] = f2b(b.x); q[5] = f2b(b.y); q[6] = f2b(b.z); q[7] = f2b(b.w);
  return r;
}

// async global->LDS, 16B per lane. LDS dest = wave-uniform base + lane*16.
__device__ __forceinline__ void gll16(const void* g, void* l) {
  __builtin_amdgcn_global_load_lds(
      (const __attribute__((address_space(1))) void*)g,
      (__attribute__((address_space(3))) void*)l, 16, 0, 0);
}

// ---------------- fp32 -> bf16 one-shot convert ------------------------------
__global__ __launch_bounds__(256) void cvt_kernel(const float* __restrict__ in,
                                                  unsigned short* __restrict__ out,
                                                  int n8) {
  for (int i = blockIdx.x * blockDim.x + threadIdx.x; i < n8;
       i += gridDim.x * blockDim.x)
    *(short8*)(out + (size_t)i * 8) = load_cvt8(in + (size_t)i * 8);
}

// ---------------- router: logits, softmax, top-2, append, aux accum ----------
__global__ __launch_bounds__(256) void router_kernel(
    const float* __restrict__ x, const float* __restrict__ rw,
    int* __restrict__ cursor, float* __restrict__ psum, int* __restrict__ t1cnt,
    int* __restrict__ tok_id, float* __restrict__ tok_w)
{
  const int lane = threadIdx.x & 63;
  const int wv   = threadIdx.x >> 6;
  const int t    = blockIdx.x * 4 + wv;
  const float* xr = x + (size_t)t * Dd;
  float acc[Ee];
#pragma unroll
  for (int e = 0; e < Ee; ++e) acc[e] = 0.f;
  for (int d = lane * 4; d < Dd; d += 256) {
    float4 xv = *(const float4*)(xr + d);
#pragma unroll
    for (int e = 0; e < Ee; ++e) {
      float4 wvv = *(const float4*)(rw + (size_t)e * Dd + d);
      acc[e] += xv.x * wvv.x + xv.y * wvv.y + xv.z * wvv.z + xv.w * wvv.w;
    }
  }
#pragma unroll
  for (int e = 0; e < Ee; ++e)
#pragma unroll
    for (int off = 32; off > 0; off >>= 1)
      acc[e] += __shfl_xor(acc[e], off, 64);

  __shared__ float s_p[4][Ee];
  __shared__ int   s_cnt[Ee];
  if (threadIdx.x < Ee) s_cnt[threadIdx.x] = 0;
  __syncthreads();

  if (lane == 0) {
    float mx = acc[0];
    for (int e = 1; e < Ee; ++e) mx = fmaxf(mx, acc[e]);
    float p[Ee]; float s = 0.f;
    for (int e = 0; e < Ee; ++e) { p[e] = __expf(acc[e] - mx); s += p[e]; }
    float inv = 1.f / s;
    for (int e = 0; e < Ee; ++e) { p[e] *= inv; s_p[wv][e] = p[e]; }
    // top-1 / top-2 by logits, ties -> lowest index (strict >)
    int e0 = 0;
    for (int e = 1; e < Ee; ++e) if (acc[e] > acc[e0]) e0 = e;
    int e1 = (e0 == 0) ? 1 : 0;
    for (int e = 0; e < Ee; ++e) if (e != e0 && acc[e] > acc[e1]) e1 = e;
    atomicAdd(&s_cnt[e0], 1);
    int pos0 = atomicAdd(&cursor[e0], 1);
    tok_id[e0 * Tt + pos0] = t; tok_w[e0 * Tt + pos0] = p[e0];
    int pos1 = atomicAdd(&cursor[e1], 1);
    tok_id[e1 * Tt + pos1] = t; tok_w[e1 * Tt + pos1] = p[e1];
  }
  __syncthreads();
  if (threadIdx.x < Ee) {
    int e = threadIdx.x;
    float s = s_p[0][e] + s_p[1][e] + s_p[2][e] + s_p[3][e];
    atomicAdd(&psum[e], s);
    int c = s_cnt[e];
    if (c) atomicAdd(&t1cnt[e], c);
  }
}

// ---------------- prep: padded bases, pad entries, aux loss ------------------
__global__ void prep_kernel(const int* __restrict__ cursor, int* __restrict__ base,
                            const float* __restrict__ psum, const int* __restrict__ t1cnt,
                            int* __restrict__ tok_id, float* __restrict__ tok_w,
                            float* __restrict__ aux_out)
{
  const int tid = threadIdx.x;
  if (tid == 0) {
    int tot = 0;
    for (int e = 0; e < Ee; ++e) { base[e] = tot; tot += (cursor[e] + 127) & ~127; }
    base[Ee] = tot;
    float s = 0.f;
    for (int e = 0; e < Ee; ++e)
      s += ((float)t1cnt[e] / (float)Tt) * (psum[e] / (float)Tt);
    aux_out[0] = 0.01f * (float)Ee * s;
  }
  for (int e = 0; e < Ee; ++e) {
    int c  = cursor[e];
    int pc = (c + 127) & ~127;
    for (int i = c + tid; i < pc; i += 256) {
      tok_id[e * Tt + i] = 0; tok_w[e * Tt + i] = 0.f;
    }
  }
}

// ---------------- GEMM1: act = silu(x@w1^T) * (x@w3^T), bf16 out ------------
// grid (11, 64, 9): z = expert (8 = shared), y = token tile, x = H tile
// Fragment-ordered LDS: tile = 8 groups of 1024B; group g holds rows 16g..16g+15,
// element (fr, koffgrp, j) at g*1024 + koffgrp*256 + fr*16 + j*2 bytes.
// A wave's af[i] read = base + group*1024 + lane*16 -> contiguous, conflict-free.
__global__ __launch_bounds__(256) void gemm1_kernel(
    const unsigned short* __restrict__ xb,
    const unsigned short* __restrict__ w1b, const unsigned short* __restrict__ w3b,
    const unsigned short* __restrict__ sw1b, const unsigned short* __restrict__ sw3b,
    const int* __restrict__ tok_id, const int* __restrict__ base,
    unsigned short* __restrict__ act_r, unsigned short* __restrict__ act_s)
{
  const int z  = blockIdx.z;
  const int m0 = blockIdx.y * 128;
  const int n0 = blockIdx.x * 128;
  const int tid = threadIdx.x;
  const unsigned short *w1p, *w3p;
  unsigned short* actp;
  int arow0;
  if (z < Ee) {
    int b0 = base[z], b1 = base[z + 1];
    if (m0 >= b1 - b0) return;
    arow0 = b0;
    w1p = w1b + (size_t)z * Hh * Dd;
    w3p = w3b + (size_t)z * Hh * Dd;
    actp = act_r;
  } else { arow0 = 0; w1p = sw1b; w3p = sw3b; actp = act_s; }

  const int lane = tid & 63;
  const int wv   = tid >> 6;
  const int fr15 = lane & 15;
  const int koff = (lane >> 4) * 8;        // k sub-offset this lane stages/reads
  const int g0 = 2 * wv, g1 = 2 * wv + 1;  // the two row-groups this wave stages

  // per-lane global sources (row gathered via tok_id for routed experts)
  int rA0 = m0 + g0 * 16 + fr15, rA1 = m0 + g1 * 16 + fr15;
  int tok0, tok1;
  if (z < Ee) { tok0 = tok_id[z * Tt + rA0]; tok1 = tok_id[z * Tt + rA1]; }
  else        { tok0 = rA0; tok1 = rA1; }
  const unsigned short* gA0 = xb + (size_t)tok0 * Dd + koff;
  const unsigned short* gA1 = xb + (size_t)tok1 * Dd + koff;
  int h0 = n0 + g0 * 16 + fr15; if (h0 >= Hh) h0 = Hh - 1;  // clamp; OOB cols zeroed in epilogue
  int h1 = n0 + g1 * 16 + fr15; if (h1 >= Hh) h1 = Hh - 1;
  const unsigned short* gB1a = w1p + (size_t)h0 * Dd + koff;
  const unsigned short* gB1b = w1p + (size_t)h1 * Dd + koff;
  const unsigned short* gB3a = w3p + (size_t)h0 * Dd + koff;
  const unsigned short* gB3b = w3p + (size_t)h1 * Dd + koff;

  __shared__ __align__(16) unsigned short lA [128 * 32];
  __shared__ __align__(16) unsigned short lB1[128 * 32];
  __shared__ __align__(16) unsigned short lB3[128 * 32];
  unsigned short* dA0  = lA  + g0 * 512; unsigned short* dA1  = lA  + g1 * 512;
  unsigned short* dB1a = lB1 + g0 * 512; unsigned short* dB1b = lB1 + g1 * 512;
  unsigned short* dB3a = lB3 + g0 * 512; unsigned short* dB3b = lB3 + g1 * 512;

  const int wm = (wv >> 1) * 64;
  const int wn = (wv & 1) * 64;
  const int gmA = wm >> 4;      // starting group of this wave's A rows
  const int gnB = wn >> 4;      // starting group of this wave's B rows
  const int lofs = lane * 8;    // ushort offset inside a group (= lane*16 B)

  float4v zero4 = {0.f, 0.f, 0.f, 0.f};
  float4v acc1[4][4], acc3[4][4];
#pragma unroll
  for (int i = 0; i < 4; ++i)
#pragma unroll
    for (int j = 0; j < 4; ++j) { acc1[i][j] = zero4; acc3[i][j] = zero4; }

  for (int k = 0; k < Dd; k += 32) {
    gll16(gA0  + k, dA0);  gll16(gA1  + k, dA1);
    gll16(gB1a + k, dB1a); gll16(gB1b + k, dB1b);
    gll16(gB3a + k, dB3a); gll16(gB3b + k, dB3b);
    __syncthreads();                       // vmcnt(0) drain: LDS data visible
    short8 af[4], bf[4];
#pragma unroll
    for (int i = 0; i < 4; ++i)
      af[i] = *(const short8*)&lA[(gmA + i) * 512 + lofs];
#pragma unroll
    for (int j = 0; j < 4; ++j)
      bf[j] = *(const short8*)&lB1[(gnB + j) * 512 + lofs];
#pragma unroll
    for (int i = 0; i < 4; ++i)
#pragma unroll
      for (int j = 0; j < 4; ++j)
        acc1[i][j] = __builtin_amdgcn_mfma_f32_16x16x32_bf16(af[i], bf[j], acc1[i][j], 0, 0, 0);
#pragma unroll
    for (int j = 0; j < 4; ++j)
      bf[j] = *(const short8*)&lB3[(gnB + j) * 512 + lofs];
#pragma unroll
    for (int i = 0; i < 4; ++i)
#pragma unroll
      for (int j = 0; j < 4; ++j)
        acc3[i][j] = __builtin_amdgcn_mfma_f32_16x16x32_bf16(af[i], bf[j], acc3[i][j], 0, 0, 0);
    __syncthreads();                       // all reads done before next overwrite
  }
  const int lr = (lane >> 4) * 4;
  const int lc = lane & 15;
#pragma unroll
  for (int i = 0; i < 4; ++i) {
#pragma unroll
    for (int r = 0; r < 4; ++r) {
      int slot = m0 + wm + i * 16 + lr + r;
      size_t arow = (size_t)(arow0 + slot) * Hp;
#pragma unroll
      for (int j = 0; j < 4; ++j) {
        int h = n0 + wn + j * 16 + lc;
        float g = acc1[i][j][r];
        float u = acc3[i][j][r];
        float val = (h < Hh) ? (g / (1.f + __expf(-g))) * u : 0.f;  // zero-fill pad cols
        actp[arow + h] = f2b(val);
      }
    }
  }
}

// ---------------- GEMM2: out (+)= w * (act @ w2^T) ---------------------------
// MODE 0: shared expert, plain stores (covers every out element exactly once).
// MODE 1: routed experts (z = blockIdx.z), atomic adds on top.
template<int MODE>
__global__ __launch_bounds__(256) void gemm2_kernel(
    const unsigned short* __restrict__ ap, const unsigned short* __restrict__ w2base,
    const int* __restrict__ tok_id, const float* __restrict__ tok_w,
    const int* __restrict__ base, float* __restrict__ out_f)
{
  const int m0 = blockIdx.y * 128;
  const int d0 = blockIdx.x * 128;
  const int tid = threadIdx.x;
  int z = 0, arow0 = 0;
  const unsigned short* w2p = w2base;
  if (MODE == 1) {
    z = blockIdx.z;
    int b0 = base[z], b1 = base[z + 1];
    if (m0 >= b1 - b0) return;
    arow0 = b0;
    w2p = w2base + (size_t)z * Dd * Hh;
  }
  const int lane = tid & 63;
  const int wv   = tid >> 6;
  const int fr15 = lane & 15;
  const int koff = (lane >> 4) * 8;
  const int g0 = 2 * wv, g1 = 2 * wv + 1;

  const unsigned short* gA0 = ap + (size_t)(arow0 + m0 + g0 * 16 + fr15) * Hp + koff;
  const unsigned short* gA1 = ap + (size_t)(arow0 + m0 + g1 * 16 + fr15) * Hp + koff;
  const unsigned short* gB0 = w2p + (size_t)(d0 + g0 * 16 + fr15) * Hh;
  const unsigned short* gB1 = w2p + (size_t)(d0 + g1 * 16 + fr15) * Hh;

  __shared__ __align__(16) unsigned short lA[128 * 32];
  __shared__ __align__(16) unsigned short lB[128 * 32];
  unsigned short* dA0 = lA + g0 * 512; unsigned short* dA1 = lA + g1 * 512;
  unsigned short* dB0 = lB + g0 * 512; unsigned short* dB1 = lB + g1 * 512;

  const int wm = (wv >> 1) * 64;
  const int wn = (wv & 1) * 64;
  const int gmA = wm >> 4;
  const int gnB = wn >> 4;
  const int lofs = lane * 8;

  float4v zero4 = {0.f, 0.f, 0.f, 0.f};
  float4v acc[4][4];
#pragma unroll
  for (int i = 0; i < 4; ++i)
#pragma unroll
    for (int j = 0; j < 4; ++j) acc[i][j] = zero4;

  for (int k = 0; k < Hp; k += 32) {
    // B rows are Hh long (unpadded): clamp k; A cols >= Hh are zero, products vanish
    int kb = k + koff; if (kb > Hh - 8) kb = Hh - 8;
    gll16(gA0 + k, dA0); gll16(gA1 + k, dA1);
    gll16(gB0 + kb, dB0); gll16(gB1 + kb, dB1);
    __syncthreads();
    short8 af[4], bf[4];
#pragma unroll
    for (int i = 0; i < 4; ++i)
      af[i] = *(const short8*)&lA[(gmA + i) * 512 + lofs];
#pragma unroll
    for (int j = 0; j < 4; ++j)
      bf[j] = *(const short8*)&lB[(gnB + j) * 512 + lofs];
#pragma unroll
    for (int i = 0; i < 4; ++i)
#pragma unroll
      for (int j = 0; j < 4; ++j)
        acc[i][j] = __builtin_amdgcn_mfma_f32_16x16x32_bf16(af[i], bf[j], acc[i][j], 0, 0, 0);
    __syncthreads();
  }
  const int lr = (lane >> 4) * 4;
  const int lc = lane & 15;
#pragma unroll
  for (int i = 0; i < 4; ++i) {
#pragma unroll
    for (int r = 0; r < 4; ++r) {
      int slot = m0 + wm + i * 16 + lr + r;
      if (MODE == 1) {
        int tok = tok_id[z * Tt + slot];
        float wgt = tok_w[z * Tt + slot];
        float* orow = out_f + (size_t)tok * Dd + d0 + wn + lc;
#pragma unroll
        for (int j = 0; j < 4; ++j)
          atomicAdd(orow + j * 16, acc[i][j][r] * wgt);
      } else {
        float* orow = out_f + (size_t)slot * Dd + d0 + wn + lc;
#pragma unroll
        for (int j = 0; j < 4; ++j)
          orow[j * 16] = acc[i][j][r];
      }
    }
  }
}

extern "C" void kernel_launch(void* const* d_in, const int* in_sizes, int n_in,
                              void* d_out, int out_size, void* d_ws, size_t ws_size,
                              hipStream_t stream)
{
  const float* x   = (const float*)d_in[0];
  const float* rw  = (const float*)d_in[1];
  const float* w1  = (const float*)d_in[2];
  const float* w2  = (const float*)d_in[3];
  const float* w3  = (const float*)d_in[4];
  const float* sw1 = (const float*)d_in[5];
  const float* sw2 = (const float*)d_in[6];
  const float* sw3 = (const float*)d_in[7];

  char* ws = (char*)d_ws;
  // layout: [0,32) cursor, [64,100) base, [128,160) psum, [160,192) t1cnt
  int*   cursor = (int*)(ws + 0);
  int*   basep  = (int*)(ws + 64);
  float* psum   = (float*)(ws + 128);
  int*   t1cnt  = (int*)(ws + 160);
  int*   tok_id = (int*)(ws + 256);                          // E*T ints
  float* tok_w  = (float*)(ws + 256 + 262144);               // E*T floats
  unsigned short* act_r = (unsigned short*)(ws + 524544);    // 17408 * Hp bf16
  unsigned short* act_s = act_r + (size_t)17408 * Hp;        // T * Hp bf16
  unsigned short* xb    = act_s + (size_t)Tt * Hp;           // T * D bf16
  unsigned short* w1b   = xb   + (size_t)Tt * Dd;            // E*H*D bf16
  unsigned short* w3b   = w1b  + (size_t)Ee * Hh * Dd;
  unsigned short* w2b   = w3b  + (size_t)Ee * Hh * Dd;       // E*D*H bf16 (rows Hh, unpadded)
  unsigned short* sw1b  = w2b  + (size_t)Ee * Dd * Hh;
  unsigned short* sw3b  = sw1b + (size_t)Hh * Dd;
  unsigned short* sw2b  = sw3b + (size_t)Hh * Dd;
  float* out_f = (float*)d_out;

  hipMemsetAsync(ws, 0, 256, stream);
  router_kernel<<<Tt / 4, 256, 0, stream>>>(x, rw, cursor, psum, t1cnt, tok_id, tok_w);
  prep_kernel<<<1, 256, 0, stream>>>(cursor, basep, psum, t1cnt, tok_id, tok_w,
                                     out_f + (size_t)Tt * Dd);
  cvt_kernel<<<2048, 256, 0, stream>>>(x,   xb,   (Tt * Dd) / 8);
  cvt_kernel<<<2048, 256, 0, stream>>>(w1,  w1b,  (Ee * Hh * Dd) / 8);
  cvt_kernel<<<2048, 256, 0, stream>>>(w3,  w3b,  (Ee * Hh * Dd) / 8);
  cvt_kernel<<<2048, 256, 0, stream>>>(w2,  w2b,  (Ee * Dd * Hh) / 8);
  cvt_kernel<<<512,  256, 0, stream>>>(sw1, sw1b, (Hh * Dd) / 8);
  cvt_kernel<<<512,  256, 0, stream>>>(sw3, sw3b, (Hh * Dd) / 8);
  cvt_kernel<<<512,  256, 0, stream>>>(sw2, sw2b, (Dd * Hh) / 8);
  gemm1_kernel<<<dim3(11, 64, 9), 256, 0, stream>>>(xb, w1b, w3b, sw1b, sw3b,
                                                    tok_id, basep, act_r, act_s);
  gemm2_kernel<0><<<dim3(16, 64, 1), 256, 0, stream>>>(act_s, sw2b, nullptr, nullptr,
                                                       nullptr, out_f);
  gemm2_kernel<1><<<dim3(16, 64, 8), 256, 0, stream>>>(act_r, w2b, tok_id, tok_w,
                                                       basep, out_f);
}

// Round 2
// 1381.750 us; speedup vs baseline: 1.8127x; 1.2569x over previous
//
#include <hip/hip_runtime.h>

#define Tt 8192     // tokens B*S
#define Dd 2048     // model dim
#define Ee 8        // routed experts
#define Hh 1368     // hidden
#define Hp 1408     // hidden padded to 11*128

using short8  = __attribute__((ext_vector_type(8))) short;
using float4v = __attribute__((ext_vector_type(4))) float;

__device__ __forceinline__ unsigned short f2b(float f) {
  union { float f; unsigned u; } v; v.f = f;
  unsigned r = v.u + 0x7fffu + ((v.u >> 16) & 1u);
  return (unsigned short)(r >> 16);
}

// load 8 consecutive fp32, RNE to bf16, pack as short8
__device__ __forceinline__ short8 load_cvt8(const float* g) {
  const float4* p = (const float4*)g;
  float4 a = p[0], b = p[1];
  short8 r;
  unsigned short* q = (unsigned short*)&r;
  q[0] = f2b(a.x); q[1] = f2b(a.y); q[2] = f2b(a.z); q[3] = f2b(a.w);
  q[4] = f2b(b.x); q[5] = f2b(b.y); q[6] = f2b(b.z); q[7] = f2b(b.w);
  return r;
}

// async global->LDS, 16B per lane. LDS dest must be wave-uniform; HW adds lane*16.
__device__ __forceinline__ void gll16(const void* g, void* l) {
  __builtin_amdgcn_global_load_lds(
      (const __attribute__((address_space(1))) void*)g,
      (__attribute__((address_space(3))) void*)l, 16, 0, 0);
}

// ---------------- fp32 -> bf16 one-shot convert ------------------------------
__global__ __launch_bounds__(256) void cvt_kernel(const float* __restrict__ in,
                                                  unsigned short* __restrict__ out,
                                                  int n8) {
  for (int i = blockIdx.x * blockDim.x + threadIdx.x; i < n8;
       i += gridDim.x * blockDim.x)
    *(short8*)(out + (size_t)i * 8) = load_cvt8(in + (size_t)i * 8);
}

// ---------------- router: logits, softmax, top-2, append, aux accum ----------
__global__ __launch_bounds__(256) void router_kernel(
    const float* __restrict__ x, const float* __restrict__ rw,
    int* __restrict__ cursor, float* __restrict__ psum, int* __restrict__ t1cnt,
    int* __restrict__ tok_id, float* __restrict__ tok_w)
{
  const int lane = threadIdx.x & 63;
  const int wv   = threadIdx.x >> 6;
  const int t    = blockIdx.x * 4 + wv;
  const float* xr = x + (size_t)t * Dd;
  float acc[Ee];
#pragma unroll
  for (int e = 0; e < Ee; ++e) acc[e] = 0.f;
  for (int d = lane * 4; d < Dd; d += 256) {
    float4 xv = *(const float4*)(xr + d);
#pragma unroll
    for (int e = 0; e < Ee; ++e) {
      float4 wvv = *(const float4*)(rw + (size_t)e * Dd + d);
      acc[e] += xv.x * wvv.x + xv.y * wvv.y + xv.z * wvv.z + xv.w * wvv.w;
    }
  }
#pragma unroll
  for (int e = 0; e < Ee; ++e)
#pragma unroll
    for (int off = 32; off > 0; off >>= 1)
      acc[e] += __shfl_xor(acc[e], off, 64);

  __shared__ float s_p[4][Ee];
  __shared__ int   s_cnt[Ee];
  if (threadIdx.x < Ee) s_cnt[threadIdx.x] = 0;
  __syncthreads();

  if (lane == 0) {
    float mx = acc[0];
    for (int e = 1; e < Ee; ++e) mx = fmaxf(mx, acc[e]);
    float p[Ee]; float s = 0.f;
    for (int e = 0; e < Ee; ++e) { p[e] = __expf(acc[e] - mx); s += p[e]; }
    float inv = 1.f / s;
    for (int e = 0; e < Ee; ++e) { p[e] *= inv; s_p[wv][e] = p[e]; }
    // top-1 / top-2 by logits, ties -> lowest index (strict >)
    int e0 = 0;
    for (int e = 1; e < Ee; ++e) if (acc[e] > acc[e0]) e0 = e;
    int e1 = (e0 == 0) ? 1 : 0;
    for (int e = 0; e < Ee; ++e) if (e != e0 && acc[e] > acc[e1]) e1 = e;
    atomicAdd(&s_cnt[e0], 1);
    int pos0 = atomicAdd(&cursor[e0], 1);
    tok_id[e0 * Tt + pos0] = t; tok_w[e0 * Tt + pos0] = p[e0];
    int pos1 = atomicAdd(&cursor[e1], 1);
    tok_id[e1 * Tt + pos1] = t; tok_w[e1 * Tt + pos1] = p[e1];
  }
  __syncthreads();
  if (threadIdx.x < Ee) {
    int e = threadIdx.x;
    float s = s_p[0][e] + s_p[1][e] + s_p[2][e] + s_p[3][e];
    atomicAdd(&psum[e], s);
    int c = s_cnt[e];
    if (c) atomicAdd(&t1cnt[e], c);
  }
}

// ---------------- prep: padded bases, pad entries, aux loss ------------------
__global__ void prep_kernel(const int* __restrict__ cursor, int* __restrict__ base,
                            const float* __restrict__ psum, const int* __restrict__ t1cnt,
                            int* __restrict__ tok_id, float* __restrict__ tok_w,
                            float* __restrict__ aux_out)
{
  const int tid = threadIdx.x;
  if (tid == 0) {
    int tot = 0;
    for (int e = 0; e < Ee; ++e) { base[e] = tot; tot += (cursor[e] + 127) & ~127; }
    base[Ee] = tot;
    float s = 0.f;
    for (int e = 0; e < Ee; ++e)
      s += ((float)t1cnt[e] / (float)Tt) * (psum[e] / (float)Tt);
    aux_out[0] = 0.01f * (float)Ee * s;
  }
  for (int e = 0; e < Ee; ++e) {
    int c  = cursor[e];
    int pc = (c + 127) & ~127;
    for (int i = c + tid; i < pc; i += 256) {
      tok_id[e * Tt + i] = 0; tok_w[e * Tt + i] = 0.f;
    }
  }
}

// ---------------- GEMM1: act = silu(x@w1^T) * (x@w3^T), bf16 out ------------
// Depth-2 pipelined: 3 LDS buffers, counted vmcnt (never 0 in steady state),
// raw s_barrier. Fragment-ordered LDS groups (1KB per 16-row group, conflict-free).
__global__ __launch_bounds__(256, 2) void gemm1_kernel(
    const unsigned short* __restrict__ xb,
    const unsigned short* __restrict__ w1b, const unsigned short* __restrict__ w3b,
    const unsigned short* __restrict__ sw1b, const unsigned short* __restrict__ sw3b,
    const int* __restrict__ tok_id, const int* __restrict__ base,
    unsigned short* __restrict__ act_r, unsigned short* __restrict__ act_s)
{
  const int z  = blockIdx.z;
  const int m0 = blockIdx.y * 128;
  const int n0 = blockIdx.x * 128;
  const int tid = threadIdx.x;
  const unsigned short *w1p, *w3p;
  unsigned short* actp;
  int arow0;
  if (z < Ee) {
    int b0 = base[z], b1 = base[z + 1];
    if (m0 >= b1 - b0) return;
    arow0 = b0;
    w1p = w1b + (size_t)z * Hh * Dd;
    w3p = w3b + (size_t)z * Hh * Dd;
    actp = act_r;
  } else { arow0 = 0; w1p = sw1b; w3p = sw3b; actp = act_s; }

  const int lane = tid & 63;
  const int wv   = tid >> 6;
  const int fr15 = lane & 15;
  const int koff = (lane >> 4) * 8;        // k sub-offset this lane stages/reads
  const int g0 = 2 * wv, g1 = 2 * wv + 1;  // row-groups this wave stages

  int rA0 = m0 + g0 * 16 + fr15, rA1 = m0 + g1 * 16 + fr15;
  int tok0, tok1;
  if (z < Ee) { tok0 = tok_id[z * Tt + rA0]; tok1 = tok_id[z * Tt + rA1]; }
  else        { tok0 = rA0; tok1 = rA1; }
  const unsigned short* gA0 = xb + (size_t)tok0 * Dd + koff;
  const unsigned short* gA1 = xb + (size_t)tok1 * Dd + koff;
  int h0 = n0 + g0 * 16 + fr15; if (h0 >= Hh) h0 = Hh - 1;  // clamp; OOB cols zeroed in epilogue
  int h1 = n0 + g1 * 16 + fr15; if (h1 >= Hh) h1 = Hh - 1;
  const unsigned short* gB1a = w1p + (size_t)h0 * Dd + koff;
  const unsigned short* gB1b = w1p + (size_t)h1 * Dd + koff;
  const unsigned short* gB3a = w3p + (size_t)h0 * Dd + koff;
  const unsigned short* gB3b = w3p + (size_t)h1 * Dd + koff;

  // 3 buffers x (A,B1,B3) x 8KB = 72KB
  __shared__ __align__(16) unsigned short sA [3 * 4096];
  __shared__ __align__(16) unsigned short sB1[3 * 4096];
  __shared__ __align__(16) unsigned short sB3[3 * 4096];

  const int wm = (wv >> 1) * 64;
  const int wn = (wv & 1) * 64;
  const int gmA = wm >> 4;
  const int gnB = wn >> 4;
  const int lofs = lane * 8;

  float4v zero4 = {0.f, 0.f, 0.f, 0.f};
  float4v acc1[4][4], acc3[4][4];
#pragma unroll
  for (int i = 0; i < 4; ++i)
#pragma unroll
    for (int j = 0; j < 4; ++j) { acc1[i][j] = zero4; acc3[i][j] = zero4; }

  auto stage = [&](int buf, int kk) {
    const int bo = buf * 4096;
    gll16(gA0  + kk, sA  + bo + g0 * 512);
    gll16(gA1  + kk, sA  + bo + g1 * 512);
    gll16(gB1a + kk, sB1 + bo + g0 * 512);
    gll16(gB1b + kk, sB1 + bo + g1 * 512);
    gll16(gB3a + kk, sB3 + bo + g0 * 512);
    gll16(gB3b + kk, sB3 + bo + g1 * 512);
  };
  auto compute = [&](int buf) {
    const int bo = buf * 4096;
    short8 af[4], bf[4];
#pragma unroll
    for (int i = 0; i < 4; ++i)
      af[i] = *(const short8*)&sA[bo + (gmA + i) * 512 + lofs];
#pragma unroll
    for (int j = 0; j < 4; ++j)
      bf[j] = *(const short8*)&sB1[bo + (gnB + j) * 512 + lofs];
#pragma unroll
    for (int i = 0; i < 4; ++i)
#pragma unroll
      for (int j = 0; j < 4; ++j)
        acc1[i][j] = __builtin_amdgcn_mfma_f32_16x16x32_bf16(af[i], bf[j], acc1[i][j], 0, 0, 0);
#pragma unroll
    for (int j = 0; j < 4; ++j)
      bf[j] = *(const short8*)&sB3[bo + (gnB + j) * 512 + lofs];
#pragma unroll
    for (int i = 0; i < 4; ++i)
#pragma unroll
      for (int j = 0; j < 4; ++j)
        acc3[i][j] = __builtin_amdgcn_mfma_f32_16x16x32_bf16(af[i], bf[j], acc3[i][j], 0, 0, 0);
  };

  const int NT = Dd / 32;  // 64
  stage(0, 0);
  stage(1, 32);
  int bC = 0, bS = 2;
  for (int t = 0; t < NT; ++t) {
    if (t + 2 < NT) {
      stage(bS, (t + 2) * 32);
      asm volatile("s_waitcnt vmcnt(12)" ::: "memory");   // tile t's 6 loads done
    } else if (t + 1 < NT) {
      asm volatile("s_waitcnt vmcnt(6)" ::: "memory");
    } else {
      asm volatile("s_waitcnt vmcnt(0)" ::: "memory");
    }
    __builtin_amdgcn_sched_barrier(0);
    __builtin_amdgcn_s_barrier();                         // all waves: tile t staged
    __builtin_amdgcn_sched_barrier(0);
    compute(bC);
    __builtin_amdgcn_sched_barrier(0);
    __builtin_amdgcn_s_barrier();                         // all reads of tile t done
    bC = (bC == 2) ? 0 : bC + 1;
    bS = (bS == 2) ? 0 : bS + 1;
  }

  const int lr = (lane >> 4) * 4;
  const int lc = lane & 15;
#pragma unroll
  for (int i = 0; i < 4; ++i) {
#pragma unroll
    for (int r = 0; r < 4; ++r) {
      int slot = m0 + wm + i * 16 + lr + r;
      size_t arow = (size_t)(arow0 + slot) * Hp;
#pragma unroll
      for (int j = 0; j < 4; ++j) {
        int h = n0 + wn + j * 16 + lc;
        float g = acc1[i][j][r];
        float u = acc3[i][j][r];
        float val = (h < Hh) ? (g / (1.f + __expf(-g))) * u : 0.f;  // zero-fill pad cols
        actp[arow + h] = f2b(val);
      }
    }
  }
}

// ---------------- GEMM2: out (+)= w * (act @ w2^T) ---------------------------
// MODE 0: shared expert, plain stores. MODE 1: routed experts, atomics on top.
// Same depth-2 pipeline.
template<int MODE>
__global__ __launch_bounds__(256, 2) void gemm2_kernel(
    const unsigned short* __restrict__ ap, const unsigned short* __restrict__ w2base,
    const int* __restrict__ tok_id, const float* __restrict__ tok_w,
    const int* __restrict__ base, float* __restrict__ out_f)
{
  const int m0 = blockIdx.y * 128;
  const int d0 = blockIdx.x * 128;
  const int tid = threadIdx.x;
  int z = 0, arow0 = 0;
  const unsigned short* w2p = w2base;
  if (MODE == 1) {
    z = blockIdx.z;
    int b0 = base[z], b1 = base[z + 1];
    if (m0 >= b1 - b0) return;
    arow0 = b0;
    w2p = w2base + (size_t)z * Dd * Hh;
  }
  const int lane = tid & 63;
  const int wv   = tid >> 6;
  const int fr15 = lane & 15;
  const int koff = (lane >> 4) * 8;
  const int g0 = 2 * wv, g1 = 2 * wv + 1;

  const unsigned short* gA0 = ap + (size_t)(arow0 + m0 + g0 * 16 + fr15) * Hp + koff;
  const unsigned short* gA1 = ap + (size_t)(arow0 + m0 + g1 * 16 + fr15) * Hp + koff;
  const unsigned short* gB0 = w2p + (size_t)(d0 + g0 * 16 + fr15) * Hh;
  const unsigned short* gB1 = w2p + (size_t)(d0 + g1 * 16 + fr15) * Hh;

  __shared__ __align__(16) unsigned short sA[3 * 4096];
  __shared__ __align__(16) unsigned short sB[3 * 4096];

  const int wm = (wv >> 1) * 64;
  const int wn = (wv & 1) * 64;
  const int gmA = wm >> 4;
  const int gnB = wn >> 4;
  const int lofs = lane * 8;

  float4v zero4 = {0.f, 0.f, 0.f, 0.f};
  float4v acc[4][4];
#pragma unroll
  for (int i = 0; i < 4; ++i)
#pragma unroll
    for (int j = 0; j < 4; ++j) acc[i][j] = zero4;

  auto stage = [&](int buf, int kk) {
    const int bo = buf * 4096;
    // B rows are Hh long (unpadded): clamp; A cols >= Hh are zero so garbage B is harmless
    int cb = kk + koff; if (cb > Hh - 8) cb = Hh - 8;
    gll16(gA0 + kk, sA + bo + g0 * 512);
    gll16(gA1 + kk, sA + bo + g1 * 512);
    gll16(gB0 + cb, sB + bo + g0 * 512);
    gll16(gB1 + cb, sB + bo + g1 * 512);
  };
  auto compute = [&](int buf) {
    const int bo = buf * 4096;
    short8 af[4], bf[4];
#pragma unroll
    for (int i = 0; i < 4; ++i)
      af[i] = *(const short8*)&sA[bo + (gmA + i) * 512 + lofs];
#pragma unroll
    for (int j = 0; j < 4; ++j)
      bf[j] = *(const short8*)&sB[bo + (gnB + j) * 512 + lofs];
#pragma unroll
    for (int i = 0; i < 4; ++i)
#pragma unroll
      for (int j = 0; j < 4; ++j)
        acc[i][j] = __builtin_amdgcn_mfma_f32_16x16x32_bf16(af[i], bf[j], acc[i][j], 0, 0, 0);
  };

  const int NT = Hp / 32;  // 44
  stage(0, 0);
  stage(1, 32);
  int bC = 0, bS = 2;
  for (int t = 0; t < NT; ++t) {
    if (t + 2 < NT) {
      stage(bS, (t + 2) * 32);
      asm volatile("s_waitcnt vmcnt(8)" ::: "memory");
    } else if (t + 1 < NT) {
      asm volatile("s_waitcnt vmcnt(4)" ::: "memory");
    } else {
      asm volatile("s_waitcnt vmcnt(0)" ::: "memory");
    }
    __builtin_amdgcn_sched_barrier(0);
    __builtin_amdgcn_s_barrier();
    __builtin_amdgcn_sched_barrier(0);
    compute(bC);
    __builtin_amdgcn_sched_barrier(0);
    __builtin_amdgcn_s_barrier();
    bC = (bC == 2) ? 0 : bC + 1;
    bS = (bS == 2) ? 0 : bS + 1;
  }

  const int lr = (lane >> 4) * 4;
  const int lc = lane & 15;
#pragma unroll
  for (int i = 0; i < 4; ++i) {
#pragma unroll
    for (int r = 0; r < 4; ++r) {
      int slot = m0 + wm + i * 16 + lr + r;
      if (MODE == 1) {
        int tok = tok_id[z * Tt + slot];
        float wgt = tok_w[z * Tt + slot];
        float* orow = out_f + (size_t)tok * Dd + d0 + wn + lc;
#pragma unroll
        for (int j = 0; j < 4; ++j)
          atomicAdd(orow + j * 16, acc[i][j][r] * wgt);
      } else {
        float* orow = out_f + (size_t)slot * Dd + d0 + wn + lc;
#pragma unroll
        for (int j = 0; j < 4; ++j)
          orow[j * 16] = acc[i][j][r];
      }
    }
  }
}

extern "C" void kernel_launch(void* const* d_in, const int* in_sizes, int n_in,
                              void* d_out, int out_size, void* d_ws, size_t ws_size,
                              hipStream_t stream)
{
  const float* x   = (const float*)d_in[0];
  const float* rw  = (const float*)d_in[1];
  const float* w1  = (const float*)d_in[2];
  const float* w2  = (const float*)d_in[3];
  const float* w3  = (const float*)d_in[4];
  const float* sw1 = (const float*)d_in[5];
  const float* sw2 = (const float*)d_in[6];
  const float* sw3 = (const float*)d_in[7];

  char* ws = (char*)d_ws;
  // layout: [0,32) cursor, [64,100) base, [128,160) psum, [160,192) t1cnt
  int*   cursor = (int*)(ws + 0);
  int*   basep  = (int*)(ws + 64);
  float* psum   = (float*)(ws + 128);
  int*   t1cnt  = (int*)(ws + 160);
  int*   tok_id = (int*)(ws + 256);                          // E*T ints
  float* tok_w  = (float*)(ws + 256 + 262144);               // E*T floats
  unsigned short* act_r = (unsigned short*)(ws + 524544);    // 17408 * Hp bf16
  unsigned short* act_s = act_r + (size_t)17408 * Hp;        // T * Hp bf16
  unsigned short* xb    = act_s + (size_t)Tt * Hp;           // T * D bf16
  unsigned short* w1b   = xb   + (size_t)Tt * Dd;            // E*H*D bf16
  unsigned short* w3b   = w1b  + (size_t)Ee * Hh * Dd;
  unsigned short* w2b   = w3b  + (size_t)Ee * Hh * Dd;       // E*D*H bf16 (rows Hh, unpadded)
  unsigned short* sw1b  = w2b  + (size_t)Ee * Dd * Hh;
  unsigned short* sw3b  = sw1b + (size_t)Hh * Dd;
  unsigned short* sw2b  = sw3b + (size_t)Hh * Dd;
  float* out_f = (float*)d_out;

  hipMemsetAsync(ws, 0, 256, stream);
  router_kernel<<<Tt / 4, 256, 0, stream>>>(x, rw, cursor, psum, t1cnt, tok_id, tok_w);
  prep_kernel<<<1, 256, 0, stream>>>(cursor, basep, psum, t1cnt, tok_id, tok_w,
                                     out_f + (size_t)Tt * Dd);
  cvt_kernel<<<2048, 256, 0, stream>>>(x,   xb,   (Tt * Dd) / 8);
  cvt_kernel<<<2048, 256, 0, stream>>>(w1,  w1b,  (Ee * Hh * Dd) / 8);
  cvt_kernel<<<2048, 256, 0, stream>>>(w3,  w3b,  (Ee * Hh * Dd) / 8);
  cvt_kernel<<<2048, 256, 0, stream>>>(w2,  w2b,  (Ee * Dd * Hh) / 8);
  cvt_kernel<<<512,  256, 0, stream>>>(sw1, sw1b, (Hh * Dd) / 8);
  cvt_kernel<<<512,  256, 0, stream>>>(sw3, sw3b, (Hh * Dd) / 8);
  cvt_kernel<<<512,  256, 0, stream>>>(sw2, sw2b, (Dd * Hh) / 8);
  gemm1_kernel<<<dim3(11, 64, 9), 256, 0, stream>>>(xb, w1b, w3b, sw1b, sw3b,
                                                    tok_id, basep, act_r, act_s);
  gemm2_kernel<0><<<dim3(16, 64, 1), 256, 0, stream>>>(act_s, sw2b, nullptr, nullptr,
                                                       nullptr, out_f);
  gemm2_kernel<1><<<dim3(16, 64, 8), 256, 0, stream>>>(act_r, w2b, tok_id, tok_w,
                                                       basep, out_f);
}